// Round 4
// baseline (7548.933 us; speedup 1.0000x reference)
//
#include <hip/hip_runtime.h>
#include <stdint.h>

typedef unsigned short ushort_t;
typedef unsigned int uint32;

#define SEQ   2048
#define BATCH 64
#define INDIM 128
#define HID   256
#define NGRP  4         // independent batch groups (16 rows each)
#define NWGG  16        // WGs per group (16 hidden cols each)
#define HSZ   (BATCH*SEQ*HID)

typedef __attribute__((ext_vector_type(8))) short short8;
typedef __attribute__((ext_vector_type(4))) float float4_t;

__device__ __forceinline__ ushort_t f2bf(float f) {
  uint32 u = __builtin_bit_cast(uint32, f);
  u += 0x7FFFu + ((u >> 16) & 1u);           // round-to-nearest-even
  return (ushort_t)(u >> 16);
}
__device__ __forceinline__ float fast_sigmoid(float x) {
  return 1.0f / (1.0f + __expf(-x));
}
__device__ __forceinline__ float fast_tanh(float x) {
  return 1.0f - 2.0f / (__expf(2.0f * x) + 1.0f);
}
template<int CTRL>
__device__ __forceinline__ float bcast_quad(float v) {
  int r = __builtin_amdgcn_mov_dpp(__builtin_bit_cast(int, v), CTRL, 0xF, 0xF, true);
  return __builtin_bit_cast(float, r);
}

// coherent (device-visible) access helpers: h + flags move via the memory-side
// Infinity Cache (sc0 sc1 => no stale per-XCD L2 copies, no cache-wide fences).
__device__ __forceinline__ void load16_bypass(short8& d, const ushort_t* p) {
  asm volatile("global_load_dwordx4 %0, %1, off sc0 sc1"
               : "=v"(d) : "v"(p) : "memory");
}
__device__ __forceinline__ void store16_bypass(ushort_t* p, short8 v) {
  asm volatile("global_store_dwordx4 %0, %1, off sc0 sc1"
               :: "v"(p), "v"(v) : "memory");
}
__device__ __forceinline__ void store_dword_bypass(uint32* p, uint32 v) {
  asm volatile("global_store_dword %0, %1, off sc0 sc1"
               :: "v"(p), "v"(v) : "memory");
}
__device__ __forceinline__ uint32 load_dword_bypass(const uint32* p) {
  uint32 v;
  asm volatile("global_load_dword %0, %1, off sc0 sc1\n\ts_waitcnt vmcnt(0)"
               : "=v"(v) : "v"(p) : "memory");
  return v;
}
__device__ __forceinline__ void drain_vm() {
  asm volatile("s_waitcnt vmcnt(0)" ::: "memory");
}

// ---------------------------------------------------------------------------
// Pack kernel.
//  BM2[( (j*4+w)*12 + kf )*512 + lane*8 + e] : bf16 B-fragments, wave-linear.
//    n = j*16 + w*4 + (llo>>2), g = llo&3, k = kf*32 + lhi*8 + e
//    val = k<256 ? W_g[k][n] : U_g[k-256][n]
//  bp2[(j*4+w)*16 + llo] = b_g[n]
//  xbf[((t*4+grp)*4+q)*512 + lane*8 + e] : bf16 A-fragments of x
//    row = grp*16 + (lane&15), k = q*32 + (lane>>4)*8 + e
//  hgrp: 4 grp x 2 buf x 16 rows x 256 cols bf16 (zeroed)
//  flags: 4 x 16 u32 (zeroed), one 64B sector per group
// ---------------------------------------------------------------------------
__global__ void pack_init(const float* __restrict__ x,
                          const float* __restrict__ Wf, const float* __restrict__ Wi,
                          const float* __restrict__ Wo, const float* __restrict__ Wc,
                          const float* __restrict__ Uf, const float* __restrict__ Ui,
                          const float* __restrict__ Uo, const float* __restrict__ Uc,
                          const float* __restrict__ bf_, const float* __restrict__ bi_,
                          const float* __restrict__ bo_, const float* __restrict__ bc_,
                          ushort_t* __restrict__ BM2, float* __restrict__ bp2,
                          ushort_t* __restrict__ xbf,
                          ushort_t* __restrict__ hgrp, uint32* __restrict__ flags) {
  int idx = blockIdx.x * 256 + threadIdx.x;   // exactly SEQ*BATCH*INDIM threads
  {
    int e = idx & 7, lane = (idx >> 3) & 63, q = (idx >> 9) & 3,
        grp = (idx >> 11) & 3, t = idx >> 13;
    if (t < SEQ) {
      int row = grp * 16 + (lane & 15);
      int k = q * 32 + (lane >> 4) * 8 + e;
      xbf[idx] = f2bf(x[(row * SEQ + t) * INDIM + k]);
    }
  }
  if (idx < 64 * 12 * 512) {                  // B fragments
    int e = idx & 7, lane = (idx >> 3) & 63;
    int kf = (idx >> 9) % 12, jw = (idx >> 9) / 12;
    int w = jw & 3, j = jw >> 2;
    int llo = lane & 15, lhi = lane >> 4;
    int n = j * 16 + w * 4 + (llo >> 2);
    int g = llo & 3;
    int k = kf * 32 + lhi * 8 + e;
    const float* W4[4] = {Wf, Wi, Wo, Wc};
    const float* U4[4] = {Uf, Ui, Uo, Uc};
    float v = (k < HID) ? W4[g][k * HID + n] : U4[g][(k - HID) * HID + n];
    BM2[idx] = f2bf(v);
  }
  if (idx < 1024) {                           // packed bias
    int llo = idx & 15, jw = idx >> 4;
    int w = jw & 3, j = jw >> 2;
    int n = j * 16 + w * 4 + (llo >> 2);
    int g = llo & 3;
    const float* B4[4] = {bf_, bi_, bo_, bc_};
    bp2[idx] = B4[g][n];
  }
  if (idx < NGRP * 2 * 16 * HID) hgrp[idx] = 0;
  if (idx < NGRP * NWGG) flags[idx] = 0;
}

// ---------------------------------------------------------------------------
// Persistent recurrence. 64 WGs x 256 thr; group i = blockIdx&3 (16 rows),
// member j = blockIdx>>2 (hidden cols 16j..16j+16, x4 gates). All 4 waves
// share the group's 16 A-rows; wave w owns 16 packed cols (4 hidden x 4 gate,
// quad-interleaved). Per step: poll 16 flags (1 sector) -> bypass-load h
// (8x16B) -> 12 MFMAs -> sigmoid gates + DPP recombine -> LDS stage ->
// wave0: ONE 512B bypass store of h + flag; wave1: ONE 64B/row out store.
// ---------------------------------------------------------------------------
__global__ __launch_bounds__(256, 1) void lstm_seq(
    const ushort_t* __restrict__ xbf, const ushort_t* __restrict__ BM2,
    const float* __restrict__ bp2, ushort_t* hgrp, uint32* flags,
    float* __restrict__ out)
{
  const int i    = blockIdx.x & 3;      // group
  const int j    = blockIdx.x >> 2;     // member within group
  const int tid  = threadIdx.x;
  const int wave = tid >> 6;
  const int lane = tid & 63;
  const int lhi  = lane >> 4;
  const int llo  = lane & 15;

  // persistent B fragments: 12 x short8 = 48 VGPRs (held all 2048 steps)
  short8 bfrag[12];
  {
    const ushort_t* bsrc = BM2 + (size_t)((j * 4 + wave) * 12) * 512 + lane * 8;
#pragma unroll
    for (int kf = 0; kf < 12; ++kf)
      bfrag[kf] = *(const short8*)(bsrc + kf * 512);
  }
  const float bias = bp2[(j * 4 + wave) * 16 + llo];

  float c_reg[4] = {0.f, 0.f, 0.f, 0.f};
  const int crow = lhi * 4;             // C-layout row base (local 0..15)
  const int nn   = llo >> 2;            // local hidden col within wave 0..3
  const int g    = lane & 3;            // gate id

  ushort_t* hg = hgrp + i * (2 * 16 * HID);     // group h double buffer

  __shared__ float    out_stage[16 * 17];
  __shared__ ushort_t hs[16 * 16];
  __shared__ float    cs[16 * 17];

  // preload x fragments for t=0 (normal cached loads, shared by group)
  short8 xq[4];
  {
    const ushort_t* xs = xbf + (size_t)(0 * 4 + i) * 2048 + lane * 8;
#pragma unroll
    for (int q = 0; q < 4; ++q) xq[q] = *(const short8*)(xs + q * 512);
  }

  for (int t = 0; t < SEQ; ++t) {
    // --- wait for all group members to finish step t-1 (stores + reads) ---
    if (t > 0) {
      uint32 v;
      do {
        v = load_dword_bypass(&flags[i * NWGG + llo]);
      } while (__any((int)(v < (uint32)t)));
      __syncthreads();   // gates stage-buffer reuse (wave1 reads of step t-1)
    }

    // --- h A-fragments: bypass loads from the group h buffer ---
    const ushort_t* hrow = hg + (t & 1) * (16 * HID) + llo * HID + lhi * 8;
    short8 hf[8];
#pragma unroll
    for (int kf = 0; kf < 8; ++kf) load16_bypass(hf[kf], hrow + kf * 32);
    asm volatile("s_waitcnt vmcnt(0)"
                 : "+v"(hf[0]), "+v"(hf[1]), "+v"(hf[2]), "+v"(hf[3]),
                   "+v"(hf[4]), "+v"(hf[5]), "+v"(hf[6]), "+v"(hf[7])
                 :: "memory");

    // --- GEMM: g = b + [h | x_t] @ [W; U] ---
    float4_t acc = {bias, bias, bias, bias};
#pragma unroll
    for (int q = 0; q < 4; ++q)
      acc = __builtin_amdgcn_mfma_f32_16x16x32_bf16(xq[q], bfrag[8 + q], acc, 0, 0, 0);
#pragma unroll
    for (int kf = 0; kf < 8; ++kf)
      acc = __builtin_amdgcn_mfma_f32_16x16x32_bf16(hf[kf], bfrag[kf], acc, 0, 0, 0);

    // --- gates (all sigmoid, per ref) + state update + LDS stage ---
#pragma unroll
    for (int r = 0; r < 4; ++r) {
      float s  = fast_sigmoid(acc[r]);
      float fv = bcast_quad<0x00>(s);
      float iv = bcast_quad<0x55>(s);
      float ov = bcast_quad<0xAA>(s);
      float cv = bcast_quad<0xFF>(s);
      float cn = fv * c_reg[r] + iv * cv;
      c_reg[r] = cn;
      float hv = ov * fast_tanh(cn);
      if (g == 0) {
        int row = crow + r;
        int col = wave * 4 + nn;               // local hidden col 0..15
        out_stage[row * 17 + col] = hv;
        hs[row * 16 + col] = f2bf(hv);
        if (t == SEQ - 1) cs[row * 17 + col] = cn;
      }
    }

    // --- prefetch x for t+1 (cached; overlaps stores/poll) ---
    if (t < SEQ - 1) {
      const ushort_t* xs = xbf + (size_t)((t + 1) * 4 + i) * 2048 + lane * 8;
#pragma unroll
      for (int q = 0; q < 4; ++q) xq[q] = *(const short8*)(xs + q * 512);
    }

    __syncthreads();   // stage complete

    if (t < SEQ - 1) {
      if (wave == 0) {
        if (lane < 32) {
          int row = lane >> 1, half = lane & 1;
          short8 v = *(const short8*)(hs + row * 16 + half * 8);
          store16_bypass(hg + ((t + 1) & 1) * (16 * HID) + row * HID +
                             j * 16 + half * 8, v);
        }
        drain_vm();                            // whole-wave store retired
        if (lane == 0)
          store_dword_bypass(&flags[i * NWGG + j], (uint32)(t + 1));
      } else if (wave == 1) {
        int row = lane >> 2, ch = lane & 3;    // 64B contiguous per row
        float4_t v = *(const float4_t*)(out_stage + row * 17 + ch * 4);
        *(float4_t*)(out + ((size_t)(16 * i + row) * SEQ + t) * HID +
                     j * 16 + ch * 4) = v;
      }
    } else {
      // final step: hidden_seq row, h_T, c_T (all 64B-aligned per WG)
      int row = lane >> 2, ch = lane & 3;
      if (wave == 1) {
        float4_t v = *(const float4_t*)(out_stage + row * 17 + ch * 4);
        *(float4_t*)(out + ((size_t)(16 * i + row) * SEQ + t) * HID +
                     j * 16 + ch * 4) = v;
      } else if (wave == 2) {
        float4_t v = *(const float4_t*)(out_stage + row * 17 + ch * 4);
        *(float4_t*)(out + HSZ + (size_t)(16 * i + row) * HID +
                     j * 16 + ch * 4) = v;
      } else if (wave == 3) {
        float4_t v = *(const float4_t*)(cs + row * 17 + ch * 4);
        *(float4_t*)(out + HSZ + BATCH * HID + (size_t)(16 * i + row) * HID +
                     j * 16 + ch * 4) = v;
      }
    }
  }
}

// ---------------------------------------------------------------------------
// Workspace layout (bytes):
//   [0, 786432)          BM2   bf16 wave-linear B fragments
//   [786432, 790528)     bp2   fp32 1024
//   [790528, 856064)     hgrp  bf16 4 grp x 2 buf x 16 x 256
//   [856064, 856320)     flags u32  4 x 16 (64B/group)
//   [1048576, 34603008)  xbf   bf16 fragment-linear x (33.5 MB)
// ---------------------------------------------------------------------------
extern "C" void kernel_launch(void* const* d_in, const int* in_sizes, int n_in,
                              void* d_out, int out_size, void* d_ws, size_t ws_size,
                              hipStream_t stream) {
  const float* xp  = (const float*)d_in[0];
  const float* Uf  = (const float*)d_in[1];
  const float* Wf  = (const float*)d_in[2];
  const float* bf_ = (const float*)d_in[3];
  const float* Ui  = (const float*)d_in[4];
  const float* Wi  = (const float*)d_in[5];
  const float* bi_ = (const float*)d_in[6];
  const float* Uo  = (const float*)d_in[7];
  const float* Wo  = (const float*)d_in[8];
  const float* bo_ = (const float*)d_in[9];
  const float* Uc  = (const float*)d_in[10];
  const float* Wc  = (const float*)d_in[11];
  const float* bc_ = (const float*)d_in[12];

  char* ws = (char*)d_ws;
  ushort_t* BM2   = (ushort_t*)(ws);
  float*    bp2   = (float*)(ws + 786432);
  ushort_t* hgrp  = (ushort_t*)(ws + 790528);
  uint32*   flags = (uint32*)(ws + 856064);
  ushort_t* xbf   = (ushort_t*)(ws + 1048576);
  float*    out   = (float*)d_out;

  pack_init<<<65536, 256, 0, stream>>>(xp, Wf, Wi, Wo, Wc, Uf, Ui, Uo, Uc,
                                       bf_, bi_, bo_, bc_, BM2, bp2, xbf,
                                       hgrp, flags);
  lstm_seq<<<NGRP * NWGG, 256, 0, stream>>>(xbf, BM2, bp2, hgrp, flags, out);
}

// Round 6
// 5154.242 us; speedup vs baseline: 1.4646x; 1.4646x over previous
//
#include <hip/hip_runtime.h>
#include <stdint.h>

typedef unsigned short ushort_t;
typedef unsigned int uint32;

#define SEQ   2048
#define BATCH 64
#define INDIM 128
#define HID   256
#define NGRP  4         // independent batch groups (16 rows each)
#define NWGG  16        // WGs per group (16 hidden cols each)
#define HSZ   (BATCH*SEQ*HID)

typedef __attribute__((ext_vector_type(8))) short short8;
typedef __attribute__((ext_vector_type(4))) float float4_t;
typedef __attribute__((ext_vector_type(2))) uint32 uint2_t;

__device__ __forceinline__ ushort_t f2bf(float f) {
  uint32 u = __builtin_bit_cast(uint32, f);
  u += 0x7FFFu + ((u >> 16) & 1u);           // round-to-nearest-even
  return (ushort_t)(u >> 16);
}
__device__ __forceinline__ float fast_sigmoid(float x) {
  return 1.0f / (1.0f + __expf(-x));
}
__device__ __forceinline__ float fast_tanh(float x) {
  return 1.0f - 2.0f / (__expf(2.0f * x) + 1.0f);
}
template<int CTRL>
__device__ __forceinline__ float bcast_quad(float v) {
  int r = __builtin_amdgcn_mov_dpp(__builtin_bit_cast(int, v), CTRL, 0xF, 0xF, true);
  return __builtin_bit_cast(float, r);
}

// Bypass (sc0 sc1) ops: coherent via the memory-side Infinity Cache.
__device__ __forceinline__ void load16_bypass(short8& d, const ushort_t* p) {
  asm volatile("global_load_dwordx4 %0, %1, off sc0 sc1"
               : "=v"(d) : "v"(p) : "memory");
}
__device__ __forceinline__ void store8_bypass(uint2_t* p, uint2_t v) {
  asm volatile("global_store_dwordx2 %0, %1, off sc0 sc1"
               :: "v"(p), "v"(v) : "memory");
}
__device__ __forceinline__ void store_dword_bypass(uint32* p, uint32 v) {
  asm volatile("global_store_dword %0, %1, off sc0 sc1"
               :: "v"(p), "v"(v) : "memory");
}
__device__ __forceinline__ uint32 load_dword_bypass(const uint32* p) {
  uint32 v;
  asm volatile("global_load_dword %0, %1, off sc0 sc1\n\ts_waitcnt vmcnt(0)"
               : "=v"(v) : "v"(p) : "memory");
  return v;
}
__device__ __forceinline__ void wait8(short8* c) {
  asm volatile("s_waitcnt vmcnt(0)"
               : "+v"(c[0]), "+v"(c[1]), "+v"(c[2]), "+v"(c[3]),
                 "+v"(c[4]), "+v"(c[5]), "+v"(c[6]), "+v"(c[7])
               :: "memory");
}
__device__ __forceinline__ void drain_vm() {
  asm volatile("s_waitcnt vmcnt(0)" ::: "memory");
}

// ---------------------------------------------------------------------------
// Pack kernel (BM2/bp2/xbf identical to validated round-4 packing).
// hpub layout (uint2 = 8B of 4 bf16 cols), per (grp,buf) 1024 units:
//   unit idx = (s>>1)*32 + row*2 + (s&1), slice s = hidden-quad 0..63
//   -> consumer reads 16B = slices {2sh,2sh+1} of one row = 8 contiguous k.
// flags[grp*64 + s] = number of steps slice s has published (zeroed here).
// ---------------------------------------------------------------------------
__global__ void pack_init(const float* __restrict__ x,
                          const float* __restrict__ Wf, const float* __restrict__ Wi,
                          const float* __restrict__ Wo, const float* __restrict__ Wc,
                          const float* __restrict__ Uf, const float* __restrict__ Ui,
                          const float* __restrict__ Uo, const float* __restrict__ Uc,
                          const float* __restrict__ bf_, const float* __restrict__ bi_,
                          const float* __restrict__ bo_, const float* __restrict__ bc_,
                          ushort_t* __restrict__ BM2, float* __restrict__ bp2,
                          ushort_t* __restrict__ xbf, uint32* __restrict__ flags) {
  int idx = blockIdx.x * 256 + threadIdx.x;   // exactly SEQ*BATCH*INDIM threads
  {
    int e = idx & 7, lane = (idx >> 3) & 63, q = (idx >> 9) & 3,
        grp = (idx >> 11) & 3, t = idx >> 13;
    if (t < SEQ) {
      int row = grp * 16 + (lane & 15);
      int k = q * 32 + (lane >> 4) * 8 + e;
      xbf[idx] = f2bf(x[(row * SEQ + t) * INDIM + k]);
    }
  }
  if (idx < 64 * 12 * 512) {                  // B fragments
    int e = idx & 7, lane = (idx >> 3) & 63;
    int kf = (idx >> 9) % 12, jw = (idx >> 9) / 12;
    int w = jw & 3, j = jw >> 2;
    int llo = lane & 15, lhi = lane >> 4;
    int n = j * 16 + w * 4 + (llo >> 2);
    int g = llo & 3;
    int k = kf * 32 + lhi * 8 + e;
    const float* W4[4] = {Wf, Wi, Wo, Wc};
    const float* U4[4] = {Uf, Ui, Uo, Uc};
    float v = (k < HID) ? W4[g][k * HID + n] : U4[g][(k - HID) * HID + n];
    BM2[idx] = f2bf(v);
  }
  if (idx < 1024) {                           // packed bias
    int llo = idx & 15, jw = idx >> 4;
    int w = jw & 3, j = jw >> 2;
    int n = j * 16 + w * 4 + (llo >> 2);
    int g = llo & 3;
    const float* B4[4] = {bf_, bi_, bo_, bc_};
    bp2[idx] = B4[g][n];
  }
  if (idx < NGRP * 64) flags[idx] = 0;
}

// ---------------------------------------------------------------------------
// Persistent recurrence, barrier-free. 64 WGs x 256 thr = 256 independent
// waves. Group i = blockIdx&3 (16 batch rows); wave owns slice j*4+w
// (4 hidden cols x 4 gates). Sync: per-slice step-counter flags in MALL.
// Consumer poll = ONE dword/lane (narrow). Data fetch = 8x dwordx4 (wide,
// once). Producer: publish 8B/lane (16 lanes) -> vmcnt drain -> flag store.
// Double-buffered h: flag>=t+2 induction guarantees buf reuse is safe.
// No __syncthreads anywhere in the loop.
// ---------------------------------------------------------------------------
__global__ __launch_bounds__(256, 1) void lstm_seq(
    const ushort_t* __restrict__ xbf, const ushort_t* __restrict__ BM2,
    const float* __restrict__ bp2, uint2_t* hpub, uint32* flags,
    float* __restrict__ out)
{
  const int i    = blockIdx.x & 3;
  const int j    = blockIdx.x >> 2;
  const int tid  = threadIdx.x;
  const int wave = tid >> 6;
  const int lane = tid & 63;
  const int lhi  = lane >> 4;
  const int llo  = lane & 15;
  const int Lr   = lane & 3;           // transpose: which r this lane takes
  const int Lq   = (lane >> 2) & 3;    // transpose: source row-quad

  // persistent B fragments (48 VGPRs, all 2048 steps)
  short8 bfrag[12];
  {
    const ushort_t* bsrc = BM2 + (size_t)((j * 4 + wave) * 12) * 512 + lane * 8;
#pragma unroll
    for (int kf = 0; kf < 12; ++kf)
      bfrag[kf] = *(const short8*)(bsrc + kf * 512);
  }
  const float bias = bp2[(j * 4 + wave) * 16 + llo];

  float c_reg[4] = {0.f, 0.f, 0.f, 0.f};
  const int sown = j * 4 + wave;                    // owned slice
  uint32* myflag = &flags[(i << 6) + sown];
  const uint32* pollp = &flags[(i << 6) + lane];

  // x fragments for t=0
  short8 xq[4];
  {
    const ushort_t* xs = xbf + (size_t)i * 2048 + lane * 8;
#pragma unroll
    for (int q = 0; q < 4; ++q) xq[q] = *(const short8*)(xs + q * 512);
  }

  for (int t = 0; t < SEQ; ++t) {
    // --- x part: independent of h ---
    float4_t acc = {bias, bias, bias, bias};
#pragma unroll
    for (int q = 0; q < 4; ++q)
      acc = __builtin_amdgcn_mfma_f32_16x16x32_bf16(xq[q], bfrag[8 + q], acc, 0, 0, 0);

    if (t > 0) {
      // --- narrow poll: all 64 slices of my group at step >= t ---
      uint32 v = load_dword_bypass(pollp);
      while (__any((int)(v < (uint32)t))) {
        __builtin_amdgcn_s_sleep(2);
        v = load_dword_bypass(pollp);
      }
      // --- wide fetch (once): h_{t-1} A-fragments, 8 x 16B bypass ---
      const ushort_t* hb = (const ushort_t*)
          (hpub + (size_t)(i * 2 + ((t - 1) & 1)) * 1024);
      short8 hf[8];
#pragma unroll
      for (int kf = 0; kf < 8; ++kf)
        load16_bypass(hf[kf], hb + (((kf * 4 + lhi) * 16 + llo) * 2) * 4);
      wait8(hf);
#pragma unroll
      for (int kf = 0; kf < 8; ++kf)
        acc = __builtin_amdgcn_mfma_f32_16x16x32_bf16(hf[kf], bfrag[kf], acc, 0, 0, 0);
    }

    // --- gates (all four sigmoid, per ref) + cell update ---
    float hv[4], cnv[4];
#pragma unroll
    for (int r = 0; r < 4; ++r) {
      float s  = fast_sigmoid(acc[r]);
      float fv = bcast_quad<0x00>(s);
      float iv = bcast_quad<0x55>(s);
      float ov = bcast_quad<0xAA>(s);
      float cv = bcast_quad<0xFF>(s);
      float cn = fv * c_reg[r] + iv * cv;
      c_reg[r] = cn;
      cnv[r] = cn;
      hv[r] = ov * fast_tanh(cn);
    }

    // --- in-register 4x4 transpose: lane L<16 gets row L's 4 hidden cols ---
    float o0 = 0.f, o1 = 0.f, o2 = 0.f, o3 = 0.f;
#pragma unroll
    for (int r = 0; r < 4; ++r) {
      int sl = Lq * 16;
      float a = __shfl(hv[r], sl + 0);
      float b = __shfl(hv[r], sl + 4);
      float c2 = __shfl(hv[r], sl + 8);
      float d = __shfl(hv[r], sl + 12);
      if (Lr == r) { o0 = a; o1 = b; o2 = c2; o3 = d; }
    }

    if (t < SEQ - 1) {
      // publish h_t slice: 8B/lane, 16 lanes
      if (lane < 16) {
        uint32 u0 = (uint32)f2bf(o0) | ((uint32)f2bf(o1) << 16);
        uint32 u1 = (uint32)f2bf(o2) | ((uint32)f2bf(o3) << 16);
        uint2_t pv = {u0, u1};
        store8_bypass(hpub + (size_t)(i * 2 + (t & 1)) * 1024 +
                      (sown >> 1) * 32 + lane * 2 + (sown & 1), pv);
      }
      drain_vm();                                  // publish retired (wave-wide)
      if (lane == 0)
        store_dword_bypass(myflag, (uint32)(t + 1));
      // out store + x prefetch: off the critical path, after the flag
      if (lane < 16) {
        float4_t ov4 = {o0, o1, o2, o3};
        *(float4_t*)(out + ((size_t)(16 * i + lane) * SEQ + t) * HID +
                     j * 16 + wave * 4) = ov4;
      }
      const ushort_t* xs = xbf + (size_t)((t + 1) * 4 + i) * 2048 + lane * 8;
#pragma unroll
      for (int q = 0; q < 4; ++q) xq[q] = *(const short8*)(xs + q * 512);
    } else {
      // final step: hidden_seq row + h_T + c_T
      if (lane < 16) {
        float4_t ov4 = {o0, o1, o2, o3};
        *(float4_t*)(out + ((size_t)(16 * i + lane) * SEQ + t) * HID +
                     j * 16 + wave * 4) = ov4;
        *(float4_t*)(out + HSZ + (size_t)(16 * i + lane) * HID +
                     j * 16 + wave * 4) = ov4;
      }
      float p0 = 0.f, p1 = 0.f, p2 = 0.f, p3 = 0.f;
#pragma unroll
      for (int r = 0; r < 4; ++r) {
        int sl = Lq * 16;
        float a = __shfl(cnv[r], sl + 0);
        float b = __shfl(cnv[r], sl + 4);
        float c2 = __shfl(cnv[r], sl + 8);
        float d = __shfl(cnv[r], sl + 12);
        if (Lr == r) { p0 = a; p1 = b; p2 = c2; p3 = d; }
      }
      if (lane < 16) {
        float4_t cv4 = {p0, p1, p2, p3};
        *(float4_t*)(out + HSZ + BATCH * HID + (size_t)(16 * i + lane) * HID +
                     j * 16 + wave * 4) = cv4;
      }
    }
  }
}

// ---------------------------------------------------------------------------
// Workspace layout (bytes):
//   [0, 786432)          BM2   bf16 wave-linear B fragments
//   [786432, 790528)     bp2   fp32 1024
//   [790528, 856064)     hpub  4 grp x 2 buf x 1024 units x 8B = 64KB
//   [856064, 857088)     flags u32 4 grp x 64 slices
//   [1048576, 34603008)  xbf   bf16 fragment-linear x (33.5 MB)
// ---------------------------------------------------------------------------
extern "C" void kernel_launch(void* const* d_in, const int* in_sizes, int n_in,
                              void* d_out, int out_size, void* d_ws, size_t ws_size,
                              hipStream_t stream) {
  const float* xp  = (const float*)d_in[0];
  const float* Uf  = (const float*)d_in[1];
  const float* Wf  = (const float*)d_in[2];
  const float* bf_ = (const float*)d_in[3];
  const float* Ui  = (const float*)d_in[4];
  const float* Wi  = (const float*)d_in[5];
  const float* bi_ = (const float*)d_in[6];
  const float* Uo  = (const float*)d_in[7];
  const float* Wo  = (const float*)d_in[8];
  const float* bo_ = (const float*)d_in[9];
  const float* Uc  = (const float*)d_in[10];
  const float* Wc  = (const float*)d_in[11];
  const float* bc_ = (const float*)d_in[12];

  char* ws = (char*)d_ws;
  ushort_t* BM2   = (ushort_t*)(ws);
  float*    bp2   = (float*)(ws + 786432);
  uint2_t*  hpub  = (uint2_t*)(ws + 790528);
  uint32*   flags = (uint32*)(ws + 856064);
  ushort_t* xbf   = (ushort_t*)(ws + 1048576);
  float*    out   = (float*)d_out;

  pack_init<<<65536, 256, 0, stream>>>(xp, Wf, Wi, Wo, Wc, Uf, Ui, Uo, Uc,
                                       bf_, bi_, bo_, bc_, BM2, bp2, xbf, flags);
  lstm_seq<<<NGRP * NWGG, 256, 0, stream>>>(xbf, BM2, bp2, hpub, flags, out);
}